// Round 6
// baseline (240.306 us; speedup 1.0000x reference)
//
#include <hip/hip_runtime.h>

// SoftPhongNormalShader, two-phase (R11 = R10 + pipelined PPT=2 streaming):
//   Phase 1: per-face table, ONE 16-B row per face (3x10-bit unorm normals
//            per dword). 1.6 MB -> L2-resident.
//   Phase 2: per-pixel shade + softmax blend, sparse color gathers
//            (gamma=1e-4 => near-argmax; only fragments within THETA of
//            z_max carry visible color; exp(-25) rel weight below cutoff).
//            NEW: each thread owns TWO pixels (t, t+P/2) and issues all 24
//            streaming dwordx4 loads up-front, then processes pixel 0 then
//            pixel 1 -> ~2x streaming lines in flight per wave.
//
// Evidence ledger: R4 dense 85us; R6 frag-parallel 113 (occupancy null);
// R7/R8 nt 177 (L2 poisoned); R9 sc0 -3.5% (L1 fill minor); R10 sparse 79.5
// (3.5x fewer line-requests -> only -7% => request COUNT not the wall).
// Streaming phase is the invariant cost: 218 MB at m13 copy-rate = 35us;
// we run at 43% of copy line-rate with all pipes idle => latency-bound,
// in-flight-line limited. R11 raises per-wave MLP 2x at 16 waves/CU
// (launch_bounds 256,4; VGPR<=128) -> net in-flight ~1.6x.

typedef float        f4 __attribute__((ext_vector_type(4)));
typedef int          i4 __attribute__((ext_vector_type(4)));
typedef unsigned int u32;
typedef u32          u4 __attribute__((ext_vector_type(4)));

#define KFRAG 8
#define SIGMA_INV 10000.0f     // 1/1e-4
#define GAMMA_INV 10000.0f     // 1/1e-4
#define ZFAR 100.0f
#define ZRANGE_INV (1.0f / 99.0f)
#define EPSV 1e-10f
#define QSCALE 1023.0f
#define QINV (1.0f / 1023.0f)
#define THETA 0.0025f          // color-gather cutoff: exp(-25) rel weight

__device__ __forceinline__ u32 pack10(float x, float y, float z) {
    u32 qx = (u32)__float2int_rn(__saturatef(x * 0.5f + 0.5f) * QSCALE);
    u32 qy = (u32)__float2int_rn(__saturatef(y * 0.5f + 0.5f) * QSCALE);
    u32 qz = (u32)__float2int_rn(__saturatef(z * 0.5f + 0.5f) * QSCALE);
    return qx | (qy << 10) | (qz << 20);
}

__global__ __launch_bounds__(256) void build_face_tab(
    const float* __restrict__ vn,     // [V,3]
    const int*   __restrict__ faces,  // [F,3]
    u4*          __restrict__ tab,    // [F] 16-B rows
    int F)
{
    int f = blockIdx.x * blockDim.x + threadIdx.x;
    if (f >= F) return;
    int v0 = faces[3*f + 0];
    int v1 = faces[3*f + 1];
    int v2 = faces[3*f + 2];
    u4 row;
    row.x = pack10(vn[3*v0], vn[3*v0+1], vn[3*v0+2]);
    row.y = pack10(vn[3*v1], vn[3*v1+1], vn[3*v1+2]);
    row.z = pack10(vn[3*v2], vn[3*v2+1], vn[3*v2+2]);
    row.w = 0;
    tab[f] = row;
}

__global__ __launch_bounds__(256, 4) void soft_phong_kernel(
    const u4*    __restrict__ tab,    // [F] packed face rows
    const float* __restrict__ bary,   // [P,K,3]
    const float* __restrict__ zbuf,   // [P,K]
    const float* __restrict__ dists,  // [P,K]
    const int*   __restrict__ p2f,    // [P,K]
    float*       __restrict__ out,    // [P,4]
    int P)
{
    int t = blockIdx.x * blockDim.x + threadIdx.x;
    int half = P >> 1;                 // P is even (N*H*W = 1048576)
    if (t >= half) return;

    // ---- issue ALL streaming loads for BOTH pixels up-front (24 dwordx4;
    //      in-order vmcnt => consuming pixel0 leaves pixel1's 12 in flight) ----
    i4 fA[2][2];
    f4 zA[2][2], dA[2][2], bA[2][6];
    #pragma unroll
    for (int i = 0; i < 2; i++) {
        size_t p = (size_t)(i == 0 ? t : t + half);
        const i4* pf4 = (const i4*)(p2f + p * KFRAG);
        fA[i][0] = pf4[0]; fA[i][1] = pf4[1];
        const f4* z4 = (const f4*)(zbuf + p * KFRAG);
        zA[i][0] = z4[0];  zA[i][1] = z4[1];
        const f4* dd4 = (const f4*)(dists + p * KFRAG);
        dA[i][0] = dd4[0]; dA[i][1] = dd4[1];
        const f4* b4 = (const f4*)(bary + p * KFRAG * 3);
        #pragma unroll
        for (int j = 0; j < 6; j++) bA[i][j] = b4[j];
    }

    // ---- process the two pixels in sequence (fully unrolled; all local
    //      array indices compile-time after unroll) ----
    #pragma unroll
    for (int i = 0; i < 2; i++) {
        int fk[KFRAG] = {fA[i][0].x, fA[i][0].y, fA[i][0].z, fA[i][0].w,
                         fA[i][1].x, fA[i][1].y, fA[i][1].z, fA[i][1].w};
        float zk[KFRAG] = {zA[i][0].x, zA[i][0].y, zA[i][0].z, zA[i][0].w,
                           zA[i][1].x, zA[i][1].y, zA[i][1].z, zA[i][1].w};
        float dk[KFRAG] = {dA[i][0].x, dA[i][0].y, dA[i][0].z, dA[i][0].w,
                           dA[i][1].x, dA[i][1].y, dA[i][1].z, dA[i][1].w};
        float bf[24];
        #pragma unroll
        for (int j = 0; j < 6; j++) {
            bf[4*j+0] = bA[i][j].x; bf[4*j+1] = bA[i][j].y;
            bf[4*j+2] = bA[i][j].z; bf[4*j+3] = bA[i][j].w;
        }

        // per-fragment prob / z_inv; pixel z_max (streaming only)
        float prob[KFRAG], zinv[KFRAG];
        float zmax = EPSV;
        #pragma unroll
        for (int k = 0; k < KFRAG; k++) {
            bool m = (fk[k] >= 0);
            prob[k] = m ? (1.0f / (1.0f + __expf(dk[k] * SIGMA_INV))) : 0.0f;
            zinv[k] = m ? ((ZFAR - zk[k]) * ZRANGE_INV) : 0.0f;
            zmax = fmaxf(zmax, zinv[k]);
        }

        // exact blend weights / denom / transparency (no gathers)
        float delta = fmaxf(__expf((EPSV - zmax) * GAMMA_INV), EPSV);
        float denom = delta;
        float trans = 1.0f;
        float wgt[KFRAG];
        #pragma unroll
        for (int k = 0; k < KFRAG; k++) {
            wgt[k] = prob[k] * __expf((zinv[k] - zmax) * GAMMA_INV);
            denom += wgt[k];
            trans *= (1.0f - prob[k]);
        }

        // SPARSE color gathers: only fragments near z_max matter
        float wr = 0.0f, wg = 0.0f, wb = 0.0f;
        #pragma unroll
        for (int k = 0; k < KFRAG; k++) {
            if (zmax - zinv[k] < THETA) {
                int fi = fk[k] >= 0 ? fk[k] : 0;
                u4 row = tab[fi];              // divergent 16-B, exec-masked
                u32 w0 = row.x, w1 = row.y, w2 = row.z;
                float b0 = bf[3*k + 0], b1 = bf[3*k + 1], b2 = bf[3*k + 2];
                // code/1023 = (n+1)/2; b0+b1+b2 = 1:
                float sx = b0 * (float)(w0 & 1023u)
                         + b1 * (float)(w1 & 1023u)
                         + b2 * (float)(w2 & 1023u);
                float sy = b0 * (float)((w0 >> 10) & 1023u)
                         + b1 * (float)((w1 >> 10) & 1023u)
                         + b2 * (float)((w2 >> 10) & 1023u);
                float sz = b0 * (float)(w0 >> 20)
                         + b1 * (float)(w1 >> 20)
                         + b2 * (float)(w2 >> 20);
                wr += wgt[k] * (sx * QINV);
                wg += wgt[k] * (1.0f - sy * QINV);
                wb += wgt[k] * (1.0f - sz * QINV);
            }
        }

        float inv = 1.0f / denom;
        f4 o = {(wr + delta) * inv, (wg + delta) * inv, (wb + delta) * inv, trans};
        int pout = (i == 0 ? t : t + half);
        __builtin_nontemporal_store(o, (f4*)out + pout);   // write-once
    }
}

extern "C" void kernel_launch(void* const* d_in, const int* in_sizes, int n_in,
                              void* d_out, int out_size, void* d_ws, size_t ws_size,
                              hipStream_t stream) {
    const float* vn    = (const float*)d_in[0];  // verts_normals [V,3]
    const float* bary  = (const float*)d_in[1];  // [N,H,W,K,3]
    const float* zbuf  = (const float*)d_in[2];  // [N,H,W,K]
    const float* dists = (const float*)d_in[3];  // [N,H,W,K]
    const int*   faces = (const int*)d_in[4];    // [F,3]
    const int*   p2f   = (const int*)d_in[5];    // [N,H,W,K]
    float* out = (float*)d_out;                  // [N,H,W,4]

    int P = in_sizes[2] / KFRAG;   // N*H*W (even: 1048576)
    int F = in_sizes[4] / 3;

    u4* tab = (u4*)d_ws;           // F * 16 B = 1.6 MB
    int block = 256;
    build_face_tab<<<(F + block - 1) / block, block, 0, stream>>>(
        vn, faces, tab, F);
    int half = P >> 1;             // 2 pixels/thread, both halves coalesced
    soft_phong_kernel<<<(half + block - 1) / block, block, 0, stream>>>(
        tab, bary, zbuf, dists, p2f, out, P);
}

// Round 7
// 234.511 us; speedup vs baseline: 1.0247x; 1.0247x over previous
//
#include <hip/hip_runtime.h>

// SoftPhongNormalShader, two-phase (R12 = R10 + SPARSE BARY reads):
//   Phase 1: per-face table, ONE 16-B row per face (3x10-bit unorm normals
//            per dword). 1.6 MB -> L2-resident.
//   Phase 2: per-pixel shade + softmax blend. gamma=1e-4 => near-argmax:
//            only fragments within THETA of z_max contribute visible color
//            (exp(-25) relative weight at the cutoff). For those (~13% of
//            fragments, ~1.02/pixel) we load BOTH the face row AND the
//            12 B of barycentrics. bary (100 MB = half of all input) is no
//            longer streamed at all.
//
// Evidence ledger: R4 dense 85us. R6 frag-parallel 113 (occupancy null).
// R7/R8 nt 177 (L2 poisoned -> latency doubled time). R9 sc0 -3.5%.
// R10 sparse tab-gathers 79.5 (3.5x fewer line-reqs -> -7%: request count
// not the wall). R11 PPT=2 85-89 (occupancy halved, per-wave MLP doesn't
// transfer). Streaming phase sustains ~2.7 TB/s effective vs m13 copy 6.3
// -> time tracks STREAMED BYTES; bary is the last big byte term.

typedef float        f4 __attribute__((ext_vector_type(4)));
typedef int          i4 __attribute__((ext_vector_type(4)));
typedef unsigned int u32;
typedef u32          u4 __attribute__((ext_vector_type(4)));

#define KFRAG 8
#define SIGMA_INV 10000.0f     // 1/1e-4
#define GAMMA_INV 10000.0f     // 1/1e-4
#define ZFAR 100.0f
#define ZRANGE_INV (1.0f / 99.0f)
#define EPSV 1e-10f
#define QSCALE 1023.0f
#define QINV (1.0f / 1023.0f)
#define THETA 0.0025f          // color cutoff: exp(-25) rel weight

__device__ __forceinline__ u32 pack10(float x, float y, float z) {
    // map [-1,1] -> [0,1023] unorm code; code/1023 == (n+1)/2
    u32 qx = (u32)__float2int_rn(__saturatef(x * 0.5f + 0.5f) * QSCALE);
    u32 qy = (u32)__float2int_rn(__saturatef(y * 0.5f + 0.5f) * QSCALE);
    u32 qz = (u32)__float2int_rn(__saturatef(z * 0.5f + 0.5f) * QSCALE);
    return qx | (qy << 10) | (qz << 20);
}

__global__ __launch_bounds__(256) void build_face_tab(
    const float* __restrict__ vn,     // [V,3]
    const int*   __restrict__ faces,  // [F,3]
    u4*          __restrict__ tab,    // [F] 16-B rows
    int F)
{
    int f = blockIdx.x * blockDim.x + threadIdx.x;
    if (f >= F) return;
    int v0 = faces[3*f + 0];
    int v1 = faces[3*f + 1];
    int v2 = faces[3*f + 2];
    u4 row;
    row.x = pack10(vn[3*v0], vn[3*v0+1], vn[3*v0+2]);
    row.y = pack10(vn[3*v1], vn[3*v1+1], vn[3*v1+2]);
    row.z = pack10(vn[3*v2], vn[3*v2+1], vn[3*v2+2]);
    row.w = 0;
    tab[f] = row;
}

__global__ __launch_bounds__(256) void soft_phong_kernel(
    const u4*    __restrict__ tab,    // [F] packed face rows
    const float* __restrict__ bary,   // [P,K,3] -- read SPARSELY
    const float* __restrict__ zbuf,   // [P,K]
    const float* __restrict__ dists,  // [P,K]
    const int*   __restrict__ p2f,    // [P,K]
    float*       __restrict__ out,    // [P,4]
    int P)
{
    int p = blockIdx.x * blockDim.x + threadIdx.x;
    if (p >= P) return;

    // ---- streaming loads (contiguous, coalesced 16-B): p2f, zbuf, dists ----
    const i4* pf4 = (const i4*)(p2f + (size_t)p * KFRAG);
    i4 fa = pf4[0], fb = pf4[1];
    int fk[KFRAG] = {fa.x, fa.y, fa.z, fa.w, fb.x, fb.y, fb.z, fb.w};

    const f4* z4 = (const f4*)(zbuf + (size_t)p * KFRAG);
    f4 za = z4[0], zb = z4[1];
    float zk[KFRAG] = {za.x, za.y, za.z, za.w, zb.x, zb.y, zb.z, zb.w};

    const f4* dd4 = (const f4*)(dists + (size_t)p * KFRAG);
    f4 da = dd4[0], db = dd4[1];
    float dk[KFRAG] = {da.x, da.y, da.z, da.w, db.x, db.y, db.z, db.w};

    // ---- per-fragment prob / z_inv; pixel z_max (streaming only) ----
    float prob[KFRAG], zinv[KFRAG];
    float zmax = EPSV;
    #pragma unroll
    for (int k = 0; k < KFRAG; k++) {
        bool m = (fk[k] >= 0);
        prob[k] = m ? (1.0f / (1.0f + __expf(dk[k] * SIGMA_INV))) : 0.0f;
        zinv[k] = m ? ((ZFAR - zk[k]) * ZRANGE_INV) : 0.0f;
        zmax = fmaxf(zmax, zinv[k]);
    }

    // ---- exact blend weights / denom / transparency (no gathers) ----
    float delta = fmaxf(__expf((EPSV - zmax) * GAMMA_INV), EPSV);
    float denom = delta;
    float trans = 1.0f;
    float wgt[KFRAG];
    #pragma unroll
    for (int k = 0; k < KFRAG; k++) {
        wgt[k] = prob[k] * __expf((zinv[k] - zmax) * GAMMA_INV);
        denom += wgt[k];
        trans *= (1.0f - prob[k]);
    }

    // ---- SPARSE color path: only fragments near z_max matter (~13%).
    //      Active lanes load the 16-B face row AND their 12 B of bary;
    //      the two loads are independent (same single latency hop). ----
    float wr = 0.0f, wg = 0.0f, wb = 0.0f;
    #pragma unroll
    for (int k = 0; k < KFRAG; k++) {
        if (zmax - zinv[k] < THETA) {
            int fi = fk[k] >= 0 ? fk[k] : 0;
            u4 row = tab[fi];                              // divergent 16-B
            const float* bp = bary + (size_t)p * (KFRAG*3) + 3*k;
            float b0 = bp[0], b1 = bp[1], b2 = bp[2];      // divergent 12-B
            u32 w0 = row.x, w1 = row.y, w2 = row.z;
            // code/1023 = (n+1)/2; b0+b1+b2 = 1:
            float sx = b0 * (float)(w0 & 1023u)
                     + b1 * (float)(w1 & 1023u)
                     + b2 * (float)(w2 & 1023u);
            float sy = b0 * (float)((w0 >> 10) & 1023u)
                     + b1 * (float)((w1 >> 10) & 1023u)
                     + b2 * (float)((w2 >> 10) & 1023u);
            float sz = b0 * (float)(w0 >> 20)
                     + b1 * (float)(w1 >> 20)
                     + b2 * (float)(w2 >> 20);
            wr += wgt[k] * (sx * QINV);
            wg += wgt[k] * (1.0f - sy * QINV);
            wb += wgt[k] * (1.0f - sz * QINV);
        }
    }

    float inv = 1.0f / denom;
    f4 o = {(wr + delta) * inv, (wg + delta) * inv, (wb + delta) * inv, trans};
    __builtin_nontemporal_store(o, (f4*)out + p);   // write-once
}

extern "C" void kernel_launch(void* const* d_in, const int* in_sizes, int n_in,
                              void* d_out, int out_size, void* d_ws, size_t ws_size,
                              hipStream_t stream) {
    const float* vn    = (const float*)d_in[0];  // verts_normals [V,3]
    const float* bary  = (const float*)d_in[1];  // [N,H,W,K,3]
    const float* zbuf  = (const float*)d_in[2];  // [N,H,W,K]
    const float* dists = (const float*)d_in[3];  // [N,H,W,K]
    const int*   faces = (const int*)d_in[4];    // [F,3]
    const int*   p2f   = (const int*)d_in[5];    // [N,H,W,K]
    float* out = (float*)d_out;                  // [N,H,W,4]

    int P = in_sizes[2] / KFRAG;   // N*H*W
    int F = in_sizes[4] / 3;

    u4* tab = (u4*)d_ws;           // F * 16 B = 1.6 MB
    int block = 256;
    build_face_tab<<<(F + block - 1) / block, block, 0, stream>>>(
        vn, faces, tab, F);
    soft_phong_kernel<<<(P + block - 1) / block, block, 0, stream>>>(
        tab, bary, zbuf, dists, p2f, out, P);
}